// Round 6
// baseline (1969.637 us; speedup 1.0000x reference)
//
#include <hip/hip_runtime.h>

typedef unsigned short u16;
typedef unsigned int u32;
typedef __attribute__((ext_vector_type(8))) short short8;
typedef __attribute__((ext_vector_type(4))) float f32x4;

__device__ __forceinline__ float bf2f(u16 u){ union{u32 i; float f;} v; v.i=((u32)u)<<16; return v.f; }
__device__ __forceinline__ u16 f2bf(float f){ union{float f; u32 i;} v; v.f=f; u32 r=v.i+0x7FFFu+((v.i>>16)&1u); return (u16)(r>>16); }

// async global->LDS, 16 bytes per lane. lds must be WAVE-UNIFORM base; HW writes
// lane i's 16B at base + i*16 (m97/m104 semantics).
__device__ __forceinline__ void glds16(const u16* g, u16* lds){
  __builtin_amdgcn_global_load_lds((const __attribute__((address_space(1))) u32*)g,
                                   (__attribute__((address_space(3))) u32*)lds, 16, 0, 0);
}

// ---------------- fp32 -> bf16 conversion ----------------
__global__ __launch_bounds__(256) void cvt_kernel(const float* __restrict__ src, u16* __restrict__ dst, int n4){
  int i = blockIdx.x*256 + threadIdx.x;
  if (i >= n4) return;
  float4 v = ((const float4*)src)[i];
  union { u16 o[4]; uint2 q; } t;
  t.o[0]=f2bf(v.x); t.o[1]=f2bf(v.y); t.o[2]=f2bf(v.z); t.o[3]=f2bf(v.w);
  ((uint2*)dst)[i] = t.q;
}

// ---------------- 256x256 deep-pipelined bf16 GEMM: C(M,N) = A(M,K) @ B(N,K)^T ----
// 8 waves (2Mx4N), BK=64, LDS 2x(A 32KB + B 32KB) = 128KB double buffer.
// Schedule per K-tile T (parity p = T&1), sync invariants:
//   region T: ds_read frags of tile T from buf[p]  (reads valid: tile T's loads
//             vmcnt-retired + barrier at tail of region T-1)
//             64 MFMA (hide ds latency; lgkmcnt auto before uses)
//             lgkmcnt(0); barrier        <- all waves done reading buf[p]
//             stage tile T+2 -> buf[p]   <- overwrite safe
//             vmcnt(8); barrier          <- own 8 newer (T+2) in flight, tile T+1
//                                           landed; barrier makes it all-waves
// Counted vmcnt(8) = loads stay in flight across barriers (T4). Never 0 mid-loop.
// T2 swizzle: 16B-slot index ^= (row&7), applied BOTH on the ds_read address and
// on the per-lane GLOBAL source of global_load_lds (linear LDS dest; rule 21 --
// same involution both sides). Makes fragment reads bank-conflict-free.
// Requires M%256==0, N%256==0, K%64==0, K>=128. EPI: 0 none, 1 +bias, 2 +bias+relu.
template<int EPI>
__global__ __launch_bounds__(512, 1) void gemm256_kernel(
    const u16* __restrict__ A, int lda,
    const u16* __restrict__ B,            // (N,K) bf16, ldb = K
    const float* __restrict__ bias,
    u16* __restrict__ C, int ldc,
    int K)
{
  const int tid = threadIdx.x;
  const int wave = tid>>6, lane = tid&63;
  const int wm = wave>>2, wn = wave&3;      // 2 x 4 wave grid
  const int lm = lane&15, quad = lane>>4;
  const int bm0 = blockIdx.x*256, bn0 = blockIdx.y*256;
  __shared__ __align__(16) u16 As[2][16384];   // [parity][256 rows x 64 cols]
  __shared__ __align__(16) u16 Bs[2][16384];
  const int NT = K >> 6;
  // stage source constants: lane covers LDS bytes [base+lane*16); logical source
  // position = linear pos with 16B-slot XOR (row&7)  (row&7 == lane>>3 here)
  const int srow = wave*8 + (lane>>3);                 // + u*64
  const int scol = ((lane&7) ^ ((lane>>3)&7)) << 3;    // swizzled k-offset (elems)
  f32x4 acc[8][4] = {};

  // prologue: stage tiles 0 and 1 (8 issues/wave each)
  #pragma unroll
  for (int t=0;t<2;t++){
    #pragma unroll
    for (int u=0;u<4;u++){
      glds16(A + (size_t)(bm0 + u*64 + srow)*lda + t*64 + scol, &As[t][u*4096 + wave*512]);
      glds16(B + (size_t)(bn0 + u*64 + srow)*K   + t*64 + scol, &Bs[t][u*4096 + wave*512]);
    }
  }
  asm volatile("s_waitcnt vmcnt(8)" ::: "memory");   // tile 0 landed (tile 1 in flight)
  __builtin_amdgcn_s_barrier();

  for (int T=0; T<NT; ++T){
    const int p = T & 1;
    // fragment reads (swizzled): slot = (ks*4+quad) ^ (lm&7)
    short8 bfr[2][4];
    #pragma unroll
    for (int ks=0;ks<2;ks++)
      #pragma unroll
      for (int j=0;j<4;j++){
        int row = wn*64 + j*16 + lm;
        bfr[ks][j] = *(const short8*)(&Bs[p][row*64 + (((ks*4+quad)^(lm&7))<<3)]);
      }
    #pragma unroll
    for (int i=0;i<8;i++){
      int row = wm*128 + i*16 + lm;
      short8 a0 = *(const short8*)(&As[p][row*64 + ((quad^(lm&7))<<3)]);
      short8 a1 = *(const short8*)(&As[p][row*64 + (((4+quad)^(lm&7))<<3)]);
      __builtin_amdgcn_s_setprio(1);
      #pragma unroll
      for (int j=0;j<4;j++){
        acc[i][j] = __builtin_amdgcn_mfma_f32_16x16x32_bf16(a0, bfr[0][j], acc[i][j], 0,0,0);
        acc[i][j] = __builtin_amdgcn_mfma_f32_16x16x32_bf16(a1, bfr[1][j], acc[i][j], 0,0,0);
      }
      __builtin_amdgcn_s_setprio(0);
    }
    if (T+1 < NT){
      asm volatile("s_waitcnt lgkmcnt(0)" ::: "memory");
      __builtin_amdgcn_s_barrier();                  // buf[p] reads complete (all waves)
      if (T+2 < NT){
        const int k0 = (T+2)*64;
        #pragma unroll
        for (int u=0;u<4;u++){
          glds16(A + (size_t)(bm0 + u*64 + srow)*lda + k0 + scol, &As[p][u*4096 + wave*512]);
          glds16(B + (size_t)(bn0 + u*64 + srow)*K   + k0 + scol, &Bs[p][u*4096 + wave*512]);
        }
        asm volatile("s_waitcnt vmcnt(8)" ::: "memory");  // tile T+1 landed, T+2 flying
      } else {
        asm volatile("s_waitcnt vmcnt(0)" ::: "memory");  // tail drain
      }
      __builtin_amdgcn_s_barrier();
    }
  }
  // epilogue
  #pragma unroll
  for (int j=0;j<4;j++){
    int col = bn0 + wn*64 + j*16 + lm;
    float bv = 0.f;
    if (EPI >= 1) bv = bias[col];
    #pragma unroll
    for (int i=0;i<8;i++){
      int r0 = bm0 + wm*128 + i*16 + quad*4;
      #pragma unroll
      for (int r=0;r<4;r++){
        float v = acc[i][j][r] + bv;
        if (EPI == 2) v = fmaxf(v, 0.f);
        C[(size_t)(r0+r)*ldc + col] = f2bf(v);
      }
    }
  }
}

// ---------------- bf16 GEMM (m97 structure), kept for small shapes ----------------
// Used only for xproj (N=64) and dt (K=32). EPI: 0 none, 1 +bias, 3 +bias+softplus.
template<int BM, int BN, int EPI>
__global__ __launch_bounds__(256, 3) void gemm_bt_kernel(
    const u16* __restrict__ A, int lda,
    const u16* __restrict__ B,            // (N,K) bf16, ldb = K
    const float* __restrict__ bias,
    u16* __restrict__ C, int ldc,
    int N, int K)
{
  constexpr int RM = BM/32, RN = BN/32;
  constexpr int AI = BM/64, BI = BN/64;   // 4096B block-issues per tile
  const int tid = threadIdx.x;
  const int wave = tid>>6, lane = tid&63;
  const int wm = wave>>1, wn = wave&1;
  const int lm = lane&15, quad = lane>>4;
  const int bm0 = blockIdx.x*BM, bn0 = blockIdx.y*BN;
  __shared__ __align__(16) u16 As[BM*32];
  __shared__ __align__(16) u16 Bs[BN*32];
  f32x4 acc[RM][RN] = {};
  const int vr = tid>>2, vc = (tid&3)<<3;
  for (int k0=0; k0<K; k0+=32){
    __syncthreads();
    #pragma unroll
    for (int i=0;i<AI;i++)
      glds16(A + (size_t)(bm0 + i*64 + vr)*lda + k0 + vc, &As[(i*256 + wave*64)*8]);
    #pragma unroll
    for (int i=0;i<BI;i++)
      glds16(B + (size_t)(bn0 + i*64 + vr)*K + k0 + vc, &Bs[(i*256 + wave*64)*8]);
    __syncthreads();
    short8 af[RM], bfr[RN];
    #pragma unroll
    for (int i=0;i<RM;i++) af[i] = *(const short8*)(&As[(wm*(BM/2)+i*16+lm)*32 + quad*8]);
    #pragma unroll
    for (int j=0;j<RN;j++) bfr[j] = *(const short8*)(&Bs[(wn*(BN/2)+j*16+lm)*32 + quad*8]);
    #pragma unroll
    for (int i=0;i<RM;i++)
      #pragma unroll
      for (int j=0;j<RN;j++)
        acc[i][j] = __builtin_amdgcn_mfma_f32_16x16x32_bf16(af[i], bfr[j], acc[i][j], 0,0,0);
  }
  #pragma unroll
  for (int j=0;j<RN;j++){
    int col = bn0 + wn*(BN/2) + j*16 + lm;
    float bv = 0.f;
    if (EPI >= 1) bv = bias[col];
    #pragma unroll
    for (int i=0;i<RM;i++){
      int r0 = bm0 + wm*(BM/2) + i*16 + quad*4;
      #pragma unroll
      for (int r=0;r<4;r++){
        float v = acc[i][j][r] + bv;
        if (EPI == 2) v = fmaxf(v, 0.f);
        if (EPI == 3) v = (v > 20.f) ? v : log1pf(__expf(v));
        C[(size_t)(r0+r)*ldc + col] = f2bf(v);
      }
    }
  }
}

// ---------------- fused attention, one block per (bt-local, head) ----------------
__global__ __launch_bounds__(256, 2) void attn_kernel(const u16* __restrict__ qkv, u16* __restrict__ o)
{
  const int bb = blockIdx.x >> 3;     // local bt index
  const int hh = blockIdx.x & 7;
  const int tid = threadIdx.x;
  const int wave = tid>>6, lane = tid&63;
  const int lm = lane&15, quad = lane>>4;
  __shared__ union {
    struct { u16 Q[128][72]; u16 K[128][72]; } qk;   // P aliases Q/K after barrier
    u16 P[128][136];
  } sm;
  __shared__ __align__(16) u16 Vt[64][136];
  const size_t base = (size_t)bb*128*1536 + (size_t)hh*64;
  #pragma unroll
  for (int i=0;i<4;i++){
    int v = i*256 + tid;
    int r = v>>3, c = (v&7)<<3;
    *(uint4*)(&sm.qk.Q[r][c]) = *(const uint4*)(qkv + base + (size_t)r*1536 + c);
    *(uint4*)(&sm.qk.K[r][c]) = *(const uint4*)(qkv + base + 512 + (size_t)r*1536 + c);
    union { uint4 q; u16 u[8]; } vv;
    vv.q = *(const uint4*)(qkv + base + 1024 + (size_t)r*1536 + c);
    #pragma unroll
    for (int j=0;j<8;j++) Vt[c+j][r] = vv.u[j];      // transposed V
  }
  __syncthreads();
  f32x4 sa[2][8] = {};
  #pragma unroll
  for (int k0=0;k0<64;k0+=32){
    short8 af[2], bfr[8];
    #pragma unroll
    for (int i=0;i<2;i++) af[i] = *(const short8*)(&sm.qk.Q[wave*32+i*16+lm][k0+quad*8]);
    #pragma unroll
    for (int j=0;j<8;j++) bfr[j] = *(const short8*)(&sm.qk.K[j*16+lm][k0+quad*8]);
    #pragma unroll
    for (int i=0;i<2;i++)
      #pragma unroll
      for (int j=0;j<8;j++)
        sa[i][j] = __builtin_amdgcn_mfma_f32_16x16x32_bf16(af[i], bfr[j], sa[i][j], 0,0,0);
  }
  __syncthreads();   // Q/K fully consumed before P overwrites
  #pragma unroll
  for (int i=0;i<2;i++){
    #pragma unroll
    for (int r=0;r<4;r++){
      float mx = -1e30f;
      #pragma unroll
      for (int j=0;j<8;j++) mx = fmaxf(mx, sa[i][j][r]);
      #pragma unroll
      for (int off=1; off<16; off<<=1) mx = fmaxf(mx, __shfl_xor(mx, off, 64));
      float pv[8]; float sum = 0.f;
      #pragma unroll
      for (int j=0;j<8;j++){ pv[j] = __expf((sa[i][j][r]-mx)*0.125f); sum += pv[j]; }
      #pragma unroll
      for (int off=1; off<16; off<<=1) sum += __shfl_xor(sum, off, 64);
      float inv = 1.f/sum;
      int row = wave*32 + i*16 + quad*4 + r;
      #pragma unroll
      for (int j=0;j<8;j++) sm.P[row][j*16+lm] = f2bf(pv[j]*inv);
    }
  }
  f32x4 oa[2][4] = {};
  #pragma unroll
  for (int k0=0;k0<128;k0+=32){
    short8 af[2], bfr[4];
    #pragma unroll
    for (int i=0;i<2;i++) af[i] = *(const short8*)(&sm.P[wave*32+i*16+lm][k0+quad*8]);
    #pragma unroll
    for (int j=0;j<4;j++) bfr[j] = *(const short8*)(&Vt[j*16+lm][k0+quad*8]);
    #pragma unroll
    for (int i=0;i<2;i++)
      #pragma unroll
      for (int j=0;j<4;j++)
        oa[i][j] = __builtin_amdgcn_mfma_f32_16x16x32_bf16(af[i], bfr[j], oa[i][j], 0,0,0);
  }
  #pragma unroll
  for (int i=0;i<2;i++)
    #pragma unroll
    for (int j=0;j<4;j++){
      int col = hh*64 + j*16 + lm;
      int r0 = wave*32 + i*16 + quad*4;
      #pragma unroll
      for (int r=0;r<4;r++)
        o[(size_t)(bb*128 + r0 + r)*512 + col] = f2bf(oa[i][j][r]);
    }
}

// ---------------- causal depthwise conv(4) + silu ----------------
__global__ __launch_bounds__(256) void conv_silu_kernel(const u16* __restrict__ xc,
    const float* __restrict__ cw, const float* __restrict__ cb, u16* __restrict__ xm)
{
  int id = blockIdx.x*256 + threadIdx.x;      // R*128 threads, 8 ch each
  int r = id >> 7, c8 = (id & 127) << 3;
  int t = r & 255;
  union { uint4 q; u16 u[8]; } rv[4];
  #pragma unroll
  for (int tap=0;tap<4;tap++){
    int ts = t - 3 + tap;
    if (ts >= 0) rv[tap].q = *(const uint4*)(xc + (size_t)(r-3+tap)*1024 + c8);
    else rv[tap].q = make_uint4(0,0,0,0);
  }
  union { uint4 q; u16 u[8]; } out;
  #pragma unroll
  for (int j=0;j<8;j++){
    float4 wj = ((const float4*)cw)[c8+j];    // conv_w (1024,1,4)
    float a = cb[c8+j];
    a += bf2f(rv[0].u[j])*wj.x + bf2f(rv[1].u[j])*wj.y + bf2f(rv[2].u[j])*wj.z + bf2f(rv[3].u[j])*wj.w;
    a = a / (1.f + __expf(-a));
    out.u[j] = f2bf(a);
  }
  *(uint4*)(xm + (size_t)r*1024 + c8) = out.q;
}

// ---------------- selective scan, y=(ys+u*D)*silu(z) fused ----------------
// v3 structure (r4 best: 145us). Fast path A[s]==-(s+1) verified at runtime;
// 2-slot prefetch; 4-way yv partials. Alias (yp==dtp) safe per program order.
typedef union { uint4 q; u16 u[8]; } BC8;
__global__ __launch_bounds__(256) void scan_kernel(
    const u16* dtp, const u16* __restrict__ xm, const u16* __restrict__ xdbl,
    const u16* __restrict__ zp, const float* __restrict__ A_log, const float* __restrict__ Dp,
    u16* yp)
{
  int bm = blockIdx.x;                        // local (b*N+n) index within chunk
  int d = blockIdx.y*256 + threadIdx.x;       // 0..1023
  float h[16];
  bool fast = true;
  #pragma unroll
  for (int s=0;s<16;s++){
    float a = __expf(A_log[d*16+s]);          // -A[s]
    float tgt = (float)(s+1);
    fast = fast && (fabsf(a - tgt) <= 1e-4f*tgt);
    h[s] = 0.f;
  }
  float Dv = Dp[d];
  size_t rowbase = (size_t)bm*256;

  float dtb[2], ub[2], zvb[2];
  BC8 b0b[2], b1b[2], c0b[2], c1b[2];
  #pragma unroll
  for (int j=0;j<2;j++){
    size_t row = rowbase + j;
    dtb[j] = bf2f(dtp[row*1024 + d]);
    ub[j]  = bf2f(xm[row*1024 + d]);
    zvb[j] = bf2f(zp[row*1024 + d]);
    const u16* bc = xdbl + row*64;
    b0b[j].q = *(const uint4*)(bc+32); b1b[j].q = *(const uint4*)(bc+40);
    c0b[j].q = *(const uint4*)(bc+48); c1b[j].q = *(const uint4*)(bc+56);
  }
  #pragma unroll 2
  for (int t=0;t<256;t++){
    const int j = t & 1;
    const float dt = dtb[j], u = ub[j], z = zvb[j];
    const BC8 b0 = b0b[j], b1 = b1b[j], c0 = c0b[j], c1 = c1b[j];
    {
      size_t rown = rowbase + ((t+2) & 255);
      dtb[j] = bf2f(dtp[rown*1024 + d]);
      ub[j]  = bf2f(xm[rown*1024 + d]);
      zvb[j] = bf2f(zp[rown*1024 + d]);
      const u16* bcn = xdbl + rown*64;
      b0b[j].q = *(const uint4*)(bcn+32); b1b[j].q = *(const uint4*)(bcn+40);
      c0b[j].q = *(const uint4*)(bcn+48); c1b[j].q = *(const uint4*)(bcn+56);
    }
    const float du = dt*u;
    float ya[4] = {0.f, 0.f, 0.f, 0.f};
    if (fast){
      float e1 = __expf(-dt);
      float e2=e1*e1, e3=e2*e1, e4=e2*e2, e5=e4*e1, e6=e4*e2, e7=e4*e3, e8=e4*e4;
      float e9=e8*e1, e10=e8*e2, e11=e8*e3, e12=e8*e4, e13=e8*e5, e14=e8*e6, e15=e8*e7, e16=e8*e8;
      float pw[16] = {e1,e2,e3,e4,e5,e6,e7,e8,e9,e10,e11,e12,e13,e14,e15,e16};
      #pragma unroll
      for (int s=0;s<8;s++){
        h[s] = pw[s]*h[s] + du*bf2f(b0.u[s]);
        ya[s&3] += h[s]*bf2f(c0.u[s]);
      }
      #pragma unroll
      for (int s=0;s<8;s++){
        h[8+s] = pw[8+s]*h[8+s] + du*bf2f(b1.u[s]);
        ya[s&3] += h[8+s]*bf2f(c1.u[s]);
      }
    } else {
      #pragma unroll
      for (int s=0;s<8;s++){
        float As = -__expf(A_log[d*16+s]);
        h[s] = __expf(dt*As)*h[s] + du*bf2f(b0.u[s]);
        ya[s&3] += h[s]*bf2f(c0.u[s]);
      }
      #pragma unroll
      for (int s=0;s<8;s++){
        float As = -__expf(A_log[d*16+8+s]);
        h[8+s] = __expf(dt*As)*h[8+s] + du*bf2f(b1.u[s]);
        ya[s&3] += h[8+s]*bf2f(c1.u[s]);
      }
    }
    const float yv = (ya[0]+ya[1]) + (ya[2]+ya[3]);
    const float o = (yv + u*Dv) * (z / (1.f + __expf(-z)));
    yp[(rowbase + t)*1024 + d] = f2bf(o);
  }
}

// ---------------- (b,t,n,:) -> (b,n,t,:) transpose, 8 bf16 per thread ----------------
__global__ __launch_bounds__(256) void transpose_kernel(const u16* __restrict__ in, u16* __restrict__ out){
  int id = blockIdx.x*256 + threadIdx.x;      // 4,194,304 threads
  int row_out = id >> 6, v = (id & 63) << 3;
  int b = row_out >> 15, rem = row_out & 32767;
  int n = rem >> 8, t = rem & 255;
  int row_in = (b*256 + t)*128 + n;
  *(uint4*)(out + (size_t)row_out*512 + v) = *(const uint4*)(in + (size_t)row_in*512 + v);
}

// ---------------- rmsnorm(main + residual) over D=512, 1 wave per row ----------------
// In-place capable (per-thread read-before-write). PERM fuses the final
// (b,n,t)->(b,t,n) permutation into the output write.
template<bool RES_F32, bool OUT_F32, bool PERM>
__global__ __launch_bounds__(256) void rmsnorm_kernel(const u16* mn,
    const void* res, const float* __restrict__ w, void* out, int rowoff)
{
  int row = blockIdx.x*4 + (threadIdx.x>>6);
  int lane = threadIdx.x & 63;
  size_t base = (size_t)row*512 + lane*8;
  union { uint4 q; u16 u[8]; } mv;
  mv.q = *(const uint4*)(mn + base);
  float vals[8];
  if (RES_F32){
    const float* rp = (const float*)res + base;
    float4 r0 = ((const float4*)rp)[0];
    float4 r1 = ((const float4*)rp)[1];
    float rr[8] = {r0.x,r0.y,r0.z,r0.w,r1.x,r1.y,r1.z,r1.w};
    #pragma unroll
    for (int j=0;j<8;j++) vals[j] = bf2f(mv.u[j]) + rr[j];
  } else {
    union { uint4 q; u16 u[8]; } rv;
    rv.q = *(const uint4*)((const u16*)res + base);
    #pragma unroll
    for (int j=0;j<8;j++) vals[j] = bf2f(mv.u[j]) + bf2f(rv.u[j]);
  }
  float ss = 0.f;
  #pragma unroll
  for (int j=0;j<8;j++) ss += vals[j]*vals[j];
  #pragma unroll
  for (int off=1; off<64; off<<=1) ss += __shfl_xor(ss, off, 64);
  float sc = rsqrtf(ss*(1.f/512.f) + 1e-5f);
  size_t obase = base;
  if (PERM){
    int g = row + rowoff;
    int p = ((g>>15)<<15) | ((g&255)<<7) | ((g>>8)&127);
    obase = (size_t)p*512 + lane*8;
  }
  if (OUT_F32){
    float* op = (float*)out + obase;
    float o[8];
    #pragma unroll
    for (int j=0;j<8;j++) o[j] = vals[j]*sc*w[lane*8+j];
    ((float4*)op)[0] = make_float4(o[0],o[1],o[2],o[3]);
    ((float4*)op)[1] = make_float4(o[4],o[5],o[6],o[7]);
  } else {
    union { uint4 q; u16 u[8]; } ov;
    #pragma unroll
    for (int j=0;j<8;j++) ov.u[j] = f2bf(vals[j]*sc*w[lane*8+j]);
    *(uint4*)((u16*)out + obase) = ov.q;
  }
}

static size_t req_bytes(int NC){
  size_t R = 65536/NC;
  size_t regB = (R*2048 > 33554432ull) ? R*2048 : 33554432ull;
  return 2ull * (4194304ull + 33554432ull + regB + R*2560ull);
}

extern "C" void kernel_launch(void* const* d_in, const int* in_sizes, int n_in,
                              void* d_out, int out_size, void* d_ws, size_t ws_size,
                              hipStream_t stream)
{
  const float* x       = (const float*)d_in[0];
  const float* w_qkv_f = (const float*)d_in[1];
  const float* b_qkv   = (const float*)d_in[2];
  const float* w_out_f = (const float*)d_in[3];
  const float* b_out   = (const float*)d_in[4];
  const float* n1w     = (const float*)d_in[5];
  const float* n2w     = (const float*)d_in[6];
  const float* n3w     = (const float*)d_in[7];
  const float* w_min_f = (const float*)d_in[8];
  const float* convw   = (const float*)d_in[9];
  const float* convb   = (const float*)d_in[10];
  const float* w_xp_f  = (const float*)d_in[11];
  const float* w_dt_f  = (const float*)d_in[12];
  const float* b_dt    = (const float*)d_in[13];
  const float* A_log   = (const float*)d_in[14];
  const float* Dp      = (const float*)d_in[15];
  const float* w_mo_f  = (const float*)d_in[16];
  const float* w_1_f   = (const float*)d_in[17];
  const float* b_1     = (const float*)d_in[18];
  const float* w_2_f   = (const float*)d_in[19];
  const float* b_2     = (const float*)d_in[20];
  float* out = (float*)d_out;
  u16* wsu = (u16*)d_ws;

  // pick chunk count: fewest chunks whose footprint fits ws_size
  int NC = 16;
  if      (ws_size >= req_bytes(1)) NC = 1;
  else if (ws_size >= req_bytes(2)) NC = 2;
  else if (ws_size >= req_bytes(4)) NC = 4;
  else if (ws_size >= req_bytes(8)) NC = 8;
  const size_t R = 65536/NC;           // token-rows per chunk

  // ---- workspace map (u16 elements) ----
  u16* w_qkv = wsu;
  u16* w_o   = w_qkv + 786432;
  u16* w_mi  = w_o   + 262144;
  u16* w_xp  = w_mi  + 1048576;
  u16* w_dt  = w_xp  + 65536;
  u16* w_mo  = w_dt  + 32768;
  u16* w_1   = w_mo  + 524288;
  u16* w_2   = w_1   + 524288;
  u16* xt    = wsu + 4194304;          // 64MB, residual through stages 2-3 (rn2 in-place)
  const size_t baseB = 37748736;
  const size_t regB  = (R*2048 > 33554432ull) ? R*2048 : 33554432ull;
  const size_t baseC = baseB + regB;
  u16* o2    = wsu + baseB;            // stage1 full (rn1 in-place -> xs1)
  u16* zb    = wsu + baseB;            // stage2 per-chunk z (R*1024)
  u16* xmb   = wsu + baseB + R*1024;   // stage2 per-chunk conv out (R*1024)
  u16* xbf_c = wsu + baseC;            // stage1 per-chunk
  u16* qkv_c = wsu + baseC + R*512;
  u16* oat_c = wsu + baseC + R*2048;
  u16* slab  = wsu + baseC;            // stage2: xc, then dt/y (R*1024)
  u16* xdbl_c= wsu + baseC + R*1024;   // R*64
  u16* mo_c  = wsu + baseC + R*1088;   // R*512
  u16* h1_c  = wsu + baseC;            // stage3 (R*1024)
  u16* h2_c  = wsu + baseC + R*1024;   // R*512

  // ---- weight conversion ----
  struct CV { const float* s; u16* d; int n; };
  const CV cvs[] = {
    {w_qkv_f, w_qkv, 786432}, {w_out_f, w_o, 262144}, {w_min_f, w_mi, 1048576},
    {w_xp_f, w_xp, 65536}, {w_dt_f, w_dt, 32768}, {w_mo_f, w_mo, 524288},
    {w_1_f, w_1, 524288}, {w_2_f, w_2, 524288},
  };
  for (int i = 0; i < 8; i++){
    int n4 = cvs[i].n / 4;
    cvt_kernel<<<(n4+255)/256, 256, 0, stream>>>(cvs[i].s, cvs[i].d, n4);
  }

  // ---- stage 1: spatial attention (chunks over (b,t)) ----
  for (int c = 0; c < NC; c++){
    cvt_kernel<<<R/2, 256, 0, stream>>>(x + c*R*512, xbf_c, (int)(R*128));
    gemm256_kernel<1><<<dim3(R/256,6), 512, 0, stream>>>(xbf_c, 512, w_qkv, b_qkv, qkv_c, 1536, 512);
    attn_kernel<<<(R/128)*8, 256, 0, stream>>>(qkv_c, oat_c);
    gemm256_kernel<1><<<dim3(R/256,2), 512, 0, stream>>>(oat_c, 512, w_o, b_out, o2 + c*R*512, 512, 512);
  }
  rmsnorm_kernel<true,false,false><<<16384, 256, 0, stream>>>(o2, x, n1w, o2, 0);   // in-place
  transpose_kernel<<<16384, 256, 0, stream>>>(o2, xt);

  // ---- stage 2: temporal mamba (chunks over (b,n)) ----
  for (int c = 0; c < NC; c++){
    const u16* xtc = xt + c*R*512;
    gemm256_kernel<0><<<dim3(R/256,4), 512, 0, stream>>>(xtc, 512, w_mi, nullptr, slab, 1024, 512);
    gemm256_kernel<0><<<dim3(R/256,4), 512, 0, stream>>>(xtc, 512, w_mi + 524288, nullptr, zb, 1024, 512);
    conv_silu_kernel<<<R/2, 256, 0, stream>>>(slab, convw, convb, xmb);
    gemm_bt_kernel<64,64,0><<<dim3(R/64,1), 256, 0, stream>>>(xmb, 1024, w_xp, nullptr, xdbl_c, 64, 64, 1024);
    gemm_bt_kernel<128,128,3><<<dim3(R/128,8), 256, 0, stream>>>(xdbl_c, 64, w_dt, b_dt, slab, 1024, 1024, 32);
    scan_kernel<<<dim3(R/256,4), 256, 0, stream>>>(slab, xmb, xdbl_c, zb, A_log, Dp, slab);  // y over dt (safe)
    gemm256_kernel<0><<<dim3(R/256,2), 512, 0, stream>>>(slab, 1024, w_mo, nullptr, mo_c, 512, 1024);
    rmsnorm_kernel<false,false,false><<<R/4, 256, 0, stream>>>(mo_c, xtc, n2w, (void*)xtc, 0); // in-place -> xt2
  }

  // ---- stage 3: MLP on (b,n,t)-ordered rows; final rmsnorm scatter-writes the
  //      (b,n,t)->(b,t,n) permutation into out (transpose fused away) ----
  for (int c = 0; c < NC; c++){
    const u16* x3c = xt + c*R*512;
    gemm256_kernel<2><<<dim3(R/256,4), 512, 0, stream>>>(x3c, 512, w_1, b_1, h1_c, 1024, 512);
    gemm256_kernel<1><<<dim3(R/256,2), 512, 0, stream>>>(h1_c, 1024, w_2, b_2, h2_c, 512, 1024);
    rmsnorm_kernel<false,true,true><<<R/4, 256, 0, stream>>>(h2_c, x3c, n3w, out, (int)(c*R));
  }
}

// Round 7
// 1835.991 us; speedup vs baseline: 1.0728x; 1.0728x over previous
//
#include <hip/hip_runtime.h>

typedef unsigned short u16;
typedef unsigned int u32;
typedef __attribute__((ext_vector_type(8))) short short8;
typedef __attribute__((ext_vector_type(4))) float f32x4;

__device__ __forceinline__ float bf2f(u16 u){ union{u32 i; float f;} v; v.i=((u32)u)<<16; return v.f; }
__device__ __forceinline__ u16 f2bf(float f){ union{float f; u32 i;} v; v.f=f; u32 r=v.i+0x7FFFu+((v.i>>16)&1u); return (u16)(r>>16); }

// async global->LDS, 16 bytes per lane. lds must be WAVE-UNIFORM base; HW writes
// lane i's 16B at base + i*16 (m97/m104 semantics). Drained by __syncthreads().
__device__ __forceinline__ void glds16(const u16* g, u16* lds){
  __builtin_amdgcn_global_load_lds((const __attribute__((address_space(1))) u32*)g,
                                   (__attribute__((address_space(3))) u32*)lds, 16, 0, 0);
}

// ---------------- fp32 -> bf16 conversion ----------------
__global__ __launch_bounds__(256) void cvt_kernel(const float* __restrict__ src, u16* __restrict__ dst, int n4){
  int i = blockIdx.x*256 + threadIdx.x;
  if (i >= n4) return;
  float4 v = ((const float4*)src)[i];
  union { u16 o[4]; uint2 q; } t;
  t.o[0]=f2bf(v.x); t.o[1]=f2bf(v.y); t.o[2]=f2bf(v.z); t.o[3]=f2bf(v.w);
  ((uint2*)dst)[i] = t.q;
}

// ---------------- bf16 GEMM (m97 structure): C(M,N) = A(M,K) @ B(N,K)^T ----------------
// global_load_lds width-16 staging into UNPADDED [rows][32] LDS tiles.
// launch_bounds(256,3): ~164 VGPR -> 3 blocks/CU; extra resident block hides the
// barrier-drain stall (m114 wave-level overlap). r5-verified best config.
// EPI: 0 none, 1 +bias, 2 +bias+relu, 3 +bias+softplus. M%BM==0, N%BN==0, K%32==0.
template<int BM, int BN, int EPI>
__global__ __launch_bounds__(256, 3) void gemm_bt_kernel(
    const u16* __restrict__ A, int lda,
    const u16* __restrict__ B,            // (N,K) bf16, ldb = K
    const float* __restrict__ bias,
    u16* __restrict__ C, int ldc,
    int N, int K)
{
  constexpr int RM = BM/32, RN = BN/32;
  constexpr int AI = BM/64, BI = BN/64;   // 4096B block-issues per tile
  const int tid = threadIdx.x;
  const int wave = tid>>6, lane = tid&63;
  const int wm = wave>>1, wn = wave&1;
  const int lm = lane&15, quad = lane>>4;
  const int bm0 = blockIdx.x*BM, bn0 = blockIdx.y*BN;
  __shared__ __align__(16) u16 As[BM*32];
  __shared__ __align__(16) u16 Bs[BN*32];
  f32x4 acc[RM][RN] = {};
  const int vr = tid>>2, vc = (tid&3)<<3;
  for (int k0=0; k0<K; k0+=32){
    __syncthreads();
    #pragma unroll
    for (int i=0;i<AI;i++)
      glds16(A + (size_t)(bm0 + i*64 + vr)*lda + k0 + vc, &As[(i*256 + wave*64)*8]);
    #pragma unroll
    for (int i=0;i<BI;i++)
      glds16(B + (size_t)(bn0 + i*64 + vr)*K + k0 + vc, &Bs[(i*256 + wave*64)*8]);
    __syncthreads();
    short8 af[RM], bfr[RN];
    #pragma unroll
    for (int i=0;i<RM;i++) af[i] = *(const short8*)(&As[(wm*(BM/2)+i*16+lm)*32 + quad*8]);
    #pragma unroll
    for (int j=0;j<RN;j++) bfr[j] = *(const short8*)(&Bs[(wn*(BN/2)+j*16+lm)*32 + quad*8]);
    #pragma unroll
    for (int i=0;i<RM;i++)
      #pragma unroll
      for (int j=0;j<RN;j++)
        acc[i][j] = __builtin_amdgcn_mfma_f32_16x16x32_bf16(af[i], bfr[j], acc[i][j], 0,0,0);
  }
  #pragma unroll
  for (int j=0;j<RN;j++){
    int col = bn0 + wn*(BN/2) + j*16 + lm;
    float bv = 0.f;
    if (EPI >= 1) bv = bias[col];
    #pragma unroll
    for (int i=0;i<RM;i++){
      int r0 = bm0 + wm*(BM/2) + i*16 + quad*4;
      #pragma unroll
      for (int r=0;r<4;r++){
        float v = acc[i][j][r] + bv;
        if (EPI == 2) v = fmaxf(v, 0.f);
        if (EPI == 3) v = (v > 20.f) ? v : log1pf(__expf(v));
        C[(size_t)(r0+r)*ldc + col] = f2bf(v);
      }
    }
  }
}

// ---------------- fused attention, one block per (bt-local, head) ----------------
// qkv: (R, 1536) bf16; o: (R, 512) bf16. LDS = 36864(QK/P union) + 16896(Vt) =
// 53760B -> 3 blocks/CU at launch_bounds(256,3) (3x53760 = 161280 <= 163840).
__global__ __launch_bounds__(256, 3) void attn_kernel(const u16* __restrict__ qkv, u16* __restrict__ o)
{
  const int bb = blockIdx.x >> 3;     // local bt index
  const int hh = blockIdx.x & 7;
  const int tid = threadIdx.x;
  const int wave = tid>>6, lane = tid&63;
  const int lm = lane&15, quad = lane>>4;
  __shared__ union {
    struct { u16 Q[128][72]; u16 K[128][72]; } qk;   // P aliases Q/K after barrier
    u16 P[128][136];
  } sm;
  __shared__ __align__(16) u16 Vt[64][132];          // stride 264B = 66 dwords -> 2 lanes/bank (free)
  const size_t base = (size_t)bb*128*1536 + (size_t)hh*64;
  #pragma unroll
  for (int i=0;i<4;i++){
    int v = i*256 + tid;
    int r = v>>3, c = (v&7)<<3;
    *(uint4*)(&sm.qk.Q[r][c]) = *(const uint4*)(qkv + base + (size_t)r*1536 + c);
    *(uint4*)(&sm.qk.K[r][c]) = *(const uint4*)(qkv + base + 512 + (size_t)r*1536 + c);
    union { uint4 q; u16 u[8]; } vv;
    vv.q = *(const uint4*)(qkv + base + 1024 + (size_t)r*1536 + c);
    #pragma unroll
    for (int j=0;j<8;j++) Vt[c+j][r] = vv.u[j];      // transposed V
  }
  __syncthreads();
  f32x4 sa[2][8] = {};
  #pragma unroll
  for (int k0=0;k0<64;k0+=32){
    short8 af[2], bfr[8];
    #pragma unroll
    for (int i=0;i<2;i++) af[i] = *(const short8*)(&sm.qk.Q[wave*32+i*16+lm][k0+quad*8]);
    #pragma unroll
    for (int j=0;j<8;j++) bfr[j] = *(const short8*)(&sm.qk.K[j*16+lm][k0+quad*8]);
    #pragma unroll
    for (int i=0;i<2;i++)
      #pragma unroll
      for (int j=0;j<8;j++)
        sa[i][j] = __builtin_amdgcn_mfma_f32_16x16x32_bf16(af[i], bfr[j], sa[i][j], 0,0,0);
  }
  __syncthreads();   // Q/K fully consumed before P overwrites
  #pragma unroll
  for (int i=0;i<2;i++){
    #pragma unroll
    for (int r=0;r<4;r++){
      float mx = -1e30f;
      #pragma unroll
      for (int j=0;j<8;j++) mx = fmaxf(mx, sa[i][j][r]);
      #pragma unroll
      for (int off=1; off<16; off<<=1) mx = fmaxf(mx, __shfl_xor(mx, off, 64));
      float pv[8]; float sum = 0.f;
      #pragma unroll
      for (int j=0;j<8;j++){ pv[j] = __expf((sa[i][j][r]-mx)*0.125f); sum += pv[j]; }
      #pragma unroll
      for (int off=1; off<16; off<<=1) sum += __shfl_xor(sum, off, 64);
      float inv = 1.f/sum;
      int row = wave*32 + i*16 + quad*4 + r;
      #pragma unroll
      for (int j=0;j<8;j++) sm.P[row][j*16+lm] = f2bf(pv[j]*inv);
    }
  }
  f32x4 oa[2][4] = {};
  #pragma unroll
  for (int k0=0;k0<128;k0+=32){
    short8 af[2], bfr[4];
    #pragma unroll
    for (int i=0;i<2;i++) af[i] = *(const short8*)(&sm.P[wave*32+i*16+lm][k0+quad*8]);
    #pragma unroll
    for (int j=0;j<4;j++) bfr[j] = *(const short8*)(&Vt[j*16+lm][k0+quad*8]);
    #pragma unroll
    for (int i=0;i<2;i++)
      #pragma unroll
      for (int j=0;j<4;j++)
        oa[i][j] = __builtin_amdgcn_mfma_f32_16x16x32_bf16(af[i], bfr[j], oa[i][j], 0,0,0);
  }
  #pragma unroll
  for (int i=0;i<2;i++)
    #pragma unroll
    for (int j=0;j<4;j++){
      int col = hh*64 + j*16 + lm;
      int r0 = wave*32 + i*16 + quad*4;
      #pragma unroll
      for (int r=0;r<4;r++)
        o[(size_t)(bb*128 + r0 + r)*512 + col] = f2bf(oa[i][j][r]);
    }
}

// ---------------- causal depthwise conv(4) + silu ----------------
__global__ __launch_bounds__(256) void conv_silu_kernel(const u16* __restrict__ xc,
    const float* __restrict__ cw, const float* __restrict__ cb, u16* __restrict__ xm)
{
  int id = blockIdx.x*256 + threadIdx.x;      // R*128 threads, 8 ch each
  int r = id >> 7, c8 = (id & 127) << 3;
  int t = r & 255;
  union { uint4 q; u16 u[8]; } rv[4];
  #pragma unroll
  for (int tap=0;tap<4;tap++){
    int ts = t - 3 + tap;
    if (ts >= 0) rv[tap].q = *(const uint4*)(xc + (size_t)(r-3+tap)*1024 + c8);
    else rv[tap].q = make_uint4(0,0,0,0);
  }
  union { uint4 q; u16 u[8]; } out;
  #pragma unroll
  for (int j=0;j<8;j++){
    float4 wj = ((const float4*)cw)[c8+j];    // conv_w (1024,1,4)
    float a = cb[c8+j];
    a += bf2f(rv[0].u[j])*wj.x + bf2f(rv[1].u[j])*wj.y + bf2f(rv[2].u[j])*wj.z + bf2f(rv[3].u[j])*wj.w;
    a = a / (1.f + __expf(-a));
    out.u[j] = f2bf(a);
  }
  *(uint4*)(xm + (size_t)r*1024 + c8) = out.q;
}

// ---------------- selective scan, y=(ys+u*D)*silu(z) fused ----------------
// v3 structure (r4 best: 145us). Fast path A[s]==-(s+1) verified at runtime;
// 2-slot prefetch; 4-way yv partials. Alias (yp==dtp) safe per program order.
typedef union { uint4 q; u16 u[8]; } BC8;
__global__ __launch_bounds__(256) void scan_kernel(
    const u16* dtp, const u16* __restrict__ xm, const u16* __restrict__ xdbl,
    const u16* __restrict__ zp, const float* __restrict__ A_log, const float* __restrict__ Dp,
    u16* yp)
{
  int bm = blockIdx.x;                        // local (b*N+n) index within chunk
  int d = blockIdx.y*256 + threadIdx.x;       // 0..1023
  float h[16];
  bool fast = true;
  #pragma unroll
  for (int s=0;s<16;s++){
    float a = __expf(A_log[d*16+s]);          // -A[s]
    float tgt = (float)(s+1);
    fast = fast && (fabsf(a - tgt) <= 1e-4f*tgt);
    h[s] = 0.f;
  }
  float Dv = Dp[d];
  size_t rowbase = (size_t)bm*256;

  float dtb[2], ub[2], zvb[2];
  BC8 b0b[2], b1b[2], c0b[2], c1b[2];
  #pragma unroll
  for (int j=0;j<2;j++){
    size_t row = rowbase + j;
    dtb[j] = bf2f(dtp[row*1024 + d]);
    ub[j]  = bf2f(xm[row*1024 + d]);
    zvb[j] = bf2f(zp[row*1024 + d]);
    const u16* bc = xdbl + row*64;
    b0b[j].q = *(const uint4*)(bc+32); b1b[j].q = *(const uint4*)(bc+40);
    c0b[j].q = *(const uint4*)(bc+48); c1b[j].q = *(const uint4*)(bc+56);
  }
  #pragma unroll 2
  for (int t=0;t<256;t++){
    const int j = t & 1;
    const float dt = dtb[j], u = ub[j], z = zvb[j];
    const BC8 b0 = b0b[j], b1 = b1b[j], c0 = c0b[j], c1 = c1b[j];
    {
      size_t rown = rowbase + ((t+2) & 255);
      dtb[j] = bf2f(dtp[rown*1024 + d]);
      ub[j]  = bf2f(xm[rown*1024 + d]);
      zvb[j] = bf2f(zp[rown*1024 + d]);
      const u16* bcn = xdbl + rown*64;
      b0b[j].q = *(const uint4*)(bcn+32); b1b[j].q = *(const uint4*)(bcn+40);
      c0b[j].q = *(const uint4*)(bcn+48); c1b[j].q = *(const uint4*)(bcn+56);
    }
    const float du = dt*u;
    float ya[4] = {0.f, 0.f, 0.f, 0.f};
    if (fast){
      float e1 = __expf(-dt);
      float e2=e1*e1, e3=e2*e1, e4=e2*e2, e5=e4*e1, e6=e4*e2, e7=e4*e3, e8=e4*e4;
      float e9=e8*e1, e10=e8*e2, e11=e8*e3, e12=e8*e4, e13=e8*e5, e14=e8*e6, e15=e8*e7, e16=e8*e8;
      float pw[16] = {e1,e2,e3,e4,e5,e6,e7,e8,e9,e10,e11,e12,e13,e14,e15,e16};
      #pragma unroll
      for (int s=0;s<8;s++){
        h[s] = pw[s]*h[s] + du*bf2f(b0.u[s]);
        ya[s&3] += h[s]*bf2f(c0.u[s]);
      }
      #pragma unroll
      for (int s=0;s<8;s++){
        h[8+s] = pw[8+s]*h[8+s] + du*bf2f(b1.u[s]);
        ya[s&3] += h[8+s]*bf2f(c1.u[s]);
      }
    } else {
      #pragma unroll
      for (int s=0;s<8;s++){
        float As = -__expf(A_log[d*16+s]);
        h[s] = __expf(dt*As)*h[s] + du*bf2f(b0.u[s]);
        ya[s&3] += h[s]*bf2f(c0.u[s]);
      }
      #pragma unroll
      for (int s=0;s<8;s++){
        float As = -__expf(A_log[d*16+8+s]);
        h[8+s] = __expf(dt*As)*h[8+s] + du*bf2f(b1.u[s]);
        ya[s&3] += h[8+s]*bf2f(c1.u[s]);
      }
    }
    const float yv = (ya[0]+ya[1]) + (ya[2]+ya[3]);
    const float o = (yv + u*Dv) * (z / (1.f + __expf(-z)));
    yp[(rowbase + t)*1024 + d] = f2bf(o);
  }
}

// ---------------- rmsnorm(main + residual) over D=512, 1 wave per row ----------------
// In-place capable (per-thread read-before-write). PERM fuses a row permutation
// into the output write (writes stay 1KB-contiguous per row = fully coalesced):
//   PERM 0: none (out row = in row)
//   PERM 1: (b,n,t)->(b,t,n)   p = (g>>15)<<15 | (g&255)<<7 | (g>>8)&127
//   PERM 2: (b,t,n)->(b,n,t)   p = (g>>15)<<15 | (g&127)<<8 | (g>>7)&255
// PERM!=0 requires out to be a distinct buffer (no in-place hazard).
template<bool RES_F32, bool OUT_F32, int PERM>
__global__ __launch_bounds__(256) void rmsnorm_kernel(const u16* mn,
    const void* res, const float* __restrict__ w, void* out, int rowoff)
{
  int row = blockIdx.x*4 + (threadIdx.x>>6);
  int lane = threadIdx.x & 63;
  size_t base = (size_t)row*512 + lane*8;
  union { uint4 q; u16 u[8]; } mv;
  mv.q = *(const uint4*)(mn + base);
  float vals[8];
  if (RES_F32){
    const float* rp = (const float*)res + base;
    float4 r0 = ((const float4*)rp)[0];
    float4 r1 = ((const float4*)rp)[1];
    float rr[8] = {r0.x,r0.y,r0.z,r0.w,r1.x,r1.y,r1.z,r1.w};
    #pragma unroll
    for (int j=0;j<8;j++) vals[j] = bf2f(mv.u[j]) + rr[j];
  } else {
    union { uint4 q; u16 u[8]; } rv;
    rv.q = *(const uint4*)((const u16*)res + base);
    #pragma unroll
    for (int j=0;j<8;j++) vals[j] = bf2f(mv.u[j]) + bf2f(rv.u[j]);
  }
  float ss = 0.f;
  #pragma unroll
  for (int j=0;j<8;j++) ss += vals[j]*vals[j];
  #pragma unroll
  for (int off=1; off<64; off<<=1) ss += __shfl_xor(ss, off, 64);
  float sc = rsqrtf(ss*(1.f/512.f) + 1e-5f);
  size_t obase = base;
  if (PERM == 1){
    int g = row + rowoff;
    int p = ((g>>15)<<15) | ((g&255)<<7) | ((g>>8)&127);
    obase = (size_t)p*512 + lane*8;
  } else if (PERM == 2){
    int g = row + rowoff;
    int p = ((g>>15)<<15) | ((g&127)<<8) | ((g>>7)&255);
    obase = (size_t)p*512 + lane*8;
  }
  if (OUT_F32){
    float* op = (float*)out + obase;
    float o[8];
    #pragma unroll
    for (int j=0;j<8;j++) o[j] = vals[j]*sc*w[lane*8+j];
    ((float4*)op)[0] = make_float4(o[0],o[1],o[2],o[3]);
    ((float4*)op)[1] = make_float4(o[4],o[5],o[6],o[7]);
  } else {
    union { uint4 q; u16 u[8]; } ov;
    #pragma unroll
    for (int j=0;j<8;j++) ov.u[j] = f2bf(vals[j]*sc*w[lane*8+j]);
    *(uint4*)((u16*)out + obase) = ov.q;
  }
}

static size_t req_bytes(int NC){
  size_t R = 65536/NC;
  size_t regB = (R*2048 > 33554432ull) ? R*2048 : 33554432ull;
  return 2ull * (4194304ull + 33554432ull + regB + R*2560ull);
}

extern "C" void kernel_launch(void* const* d_in, const int* in_sizes, int n_in,
                              void* d_out, int out_size, void* d_ws, size_t ws_size,
                              hipStream_t stream)
{
  const float* x       = (const float*)d_in[0];
  const float* w_qkv_f = (const float*)d_in[1];
  const float* b_qkv   = (const float*)d_in[2];
  const float* w_out_f = (const float*)d_in[3];
  const float* b_out   = (const float*)d_in[4];
  const float* n1w     = (const float*)d_in[5];
  const float* n2w     = (const float*)d_in[6];
  const float* n3w     = (const float*)d_in[7];
  const float* w_min_f = (const float*)d_in[8];
  const float* convw   = (const float*)d_in[9];
  const float* convb   = (const float*)d_in[10];
  const float* w_xp_f  = (const float*)d_in[11];
  const float* w_dt_f  = (const float*)d_in[12];
  const float* b_dt    = (const float*)d_in[13];
  const float* A_log   = (const float*)d_in[14];
  const float* Dp      = (const float*)d_in[15];
  const float* w_mo_f  = (const float*)d_in[16];
  const float* w_1_f   = (const float*)d_in[17];
  const float* b_1     = (const float*)d_in[18];
  const float* w_2_f   = (const float*)d_in[19];
  const float* b_2     = (const float*)d_in[20];
  float* out = (float*)d_out;
  u16* wsu = (u16*)d_ws;

  // pick chunk count: fewest chunks whose footprint fits ws_size
  int NC = 16;
  if      (ws_size >= req_bytes(1)) NC = 1;
  else if (ws_size >= req_bytes(2)) NC = 2;
  else if (ws_size >= req_bytes(4)) NC = 4;
  else if (ws_size >= req_bytes(8)) NC = 8;
  const size_t R = 65536/NC;           // token-rows per chunk

  // ---- workspace map (u16 elements) ----
  u16* w_qkv = wsu;
  u16* w_o   = w_qkv + 786432;
  u16* w_mi  = w_o   + 262144;
  u16* w_xp  = w_mi  + 1048576;
  u16* w_dt  = w_xp  + 65536;
  u16* w_mo  = w_dt  + 32768;
  u16* w_1   = w_mo  + 524288;
  u16* w_2   = w_1   + 524288;
  u16* xt    = wsu + 4194304;          // 64MB, residual through stages 2-3 (rn2 in-place)
  const size_t baseB = 37748736;
  const size_t regB  = (R*2048 > 33554432ull) ? R*2048 : 33554432ull;
  const size_t baseC = baseB + regB;
  u16* o2    = wsu + baseB;            // stage1 full
  u16* zb    = wsu + baseB;            // stage2 per-chunk z (R*1024)
  u16* xmb   = wsu + baseB + R*1024;   // stage2 per-chunk conv out (R*1024)
  u16* xbf_c = wsu + baseC;            // stage1 per-chunk
  u16* qkv_c = wsu + baseC + R*512;
  u16* oat_c = wsu + baseC + R*2048;
  u16* slab  = wsu + baseC;            // stage2: xc, then dt/y (R*1024)
  u16* xdbl_c= wsu + baseC + R*1024;   // R*64
  u16* mo_c  = wsu + baseC + R*1088;   // R*512
  u16* h1_c  = wsu + baseC;            // stage3 (R*1024)
  u16* h2_c  = wsu + baseC + R*1024;   // R*512

  // ---- weight conversion ----
  struct CV { const float* s; u16* d; int n; };
  const CV cvs[] = {
    {w_qkv_f, w_qkv, 786432}, {w_out_f, w_o, 262144}, {w_min_f, w_mi, 1048576},
    {w_xp_f, w_xp, 65536}, {w_dt_f, w_dt, 32768}, {w_mo_f, w_mo, 524288},
    {w_1_f, w_1, 524288}, {w_2_f, w_2, 524288},
  };
  for (int i = 0; i < 8; i++){
    int n4 = cvs[i].n / 4;
    cvt_kernel<<<(n4+255)/256, 256, 0, stream>>>(cvs[i].s, cvs[i].d, n4);
  }

  // ---- stage 1: spatial attention (chunks over (b,t)) ----
  for (int c = 0; c < NC; c++){
    cvt_kernel<<<R/2, 256, 0, stream>>>(x + c*R*512, xbf_c, (int)(R*128));
    gemm_bt_kernel<128,128,1><<<dim3(R/128,12), 256, 0, stream>>>(xbf_c, 512, w_qkv, b_qkv, qkv_c, 1536, 1536, 512);
    attn_kernel<<<(R/128)*8, 256, 0, stream>>>(qkv_c, oat_c);
    gemm_bt_kernel<128,128,1><<<dim3(R/128,4), 256, 0, stream>>>(oat_c, 512, w_o, b_out, o2 + c*R*512, 512, 512, 512);
  }
  // rn1 with fused (b,t,n)->(b,n,t) permutation directly into xt (transpose deleted)
  rmsnorm_kernel<true,false,2><<<16384, 256, 0, stream>>>(o2, x, n1w, xt, 0);

  // ---- stage 2: temporal mamba (chunks over (b,n)) ----
  for (int c = 0; c < NC; c++){
    const u16* xtc = xt + c*R*512;
    gemm_bt_kernel<128,128,0><<<dim3(R/128,8), 256, 0, stream>>>(xtc, 512, w_mi, nullptr, slab, 1024, 1024, 512);
    gemm_bt_kernel<128,128,0><<<dim3(R/128,8), 256, 0, stream>>>(xtc, 512, w_mi + 524288, nullptr, zb, 1024, 1024, 512);
    conv_silu_kernel<<<R/2, 256, 0, stream>>>(slab, convw, convb, xmb);
    gemm_bt_kernel<64,64,0><<<dim3(R/64,1), 256, 0, stream>>>(xmb, 1024, w_xp, nullptr, xdbl_c, 64, 64, 1024);
    gemm_bt_kernel<128,128,3><<<dim3(R/128,8), 256, 0, stream>>>(xdbl_c, 64, w_dt, b_dt, slab, 1024, 1024, 32);
    scan_kernel<<<dim3(R/256,4), 256, 0, stream>>>(slab, xmb, xdbl_c, zb, A_log, Dp, slab);  // y over dt (safe)
    gemm_bt_kernel<128,128,0><<<dim3(R/128,4), 256, 0, stream>>>(slab, 1024, w_mo, nullptr, mo_c, 512, 512, 1024);
    rmsnorm_kernel<false,false,0><<<R/4, 256, 0, stream>>>(mo_c, xtc, n2w, (void*)xtc, 0);   // in-place -> xt2
  }

  // ---- stage 3: MLP on (b,n,t)-ordered rows; final rmsnorm scatter-writes the
  //      (b,n,t)->(b,t,n) permutation into out (transpose fused away) ----
  for (int c = 0; c < NC; c++){
    const u16* x3c = xt + c*R*512;
    gemm_bt_kernel<128,128,2><<<dim3(R/128,8), 256, 0, stream>>>(x3c, 512, w_1, b_1, h1_c, 1024, 1024, 512);
    gemm_bt_kernel<128,128,1><<<dim3(R/128,4), 256, 0, stream>>>(h1_c, 1024, w_2, b_2, h2_c, 512, 512, 1024);
    rmsnorm_kernel<false,true,1><<<R/4, 256, 0, stream>>>(h2_c, x3c, n3w, out, (int)(c*R));
  }
}